// Round 1
// baseline (56953.485 us; speedup 1.0000x reference)
//
#include <hip/hip_runtime.h>
#include <hip/hip_bf16.h>

#define NN 100000
#define EE 3200000
#define CC 64
#define NC (NN*CC)

// ---------------- dtype helpers ----------------
__device__ __forceinline__ float ldf(const void* p, int i, int isbf) {
    if (isbf) {
        unsigned int u = ((const unsigned short*)p)[i];
        return __uint_as_float(u << 16);
    }
    return ((const float*)p)[i];
}

// ---------------- detection ----------------
// flags[0]: 1 if float arrays (y_soft/y_true/out) are bf16, else fp32
// flags[1]: 1 if mask is byte-bool, else int32
__global__ void detect_kernel(const void* ytrue, const void* mask, int* flags) {
    int tid = blockIdx.x * blockDim.x + threadIdx.x;
    int stride = gridDim.x * blockDim.x;
    const unsigned int* w = (const unsigned int*)ytrue;
    int nb = 0, nm = 0;
    for (int i = tid; i < NC / 2; i += stride) {
        if ((w[i] & 0xFFFFu) == 0x3F80u) nb = 1;
    }
    const unsigned char* mb = (const unsigned char*)mask;
    for (int i = tid; i < NN; i += stride) {
        if ((i & 3) != 0 && mb[i] != 0) nm = 1;
    }
    if (nb) atomicOr(&flags[0], 1);
    if (nm) atomicOr(&flags[1], 1);
}

// ---------------- prep: labels, mask01, numel ----------------
__global__ void prep_kernel(const void* ytrue, const void* mask, const int* flags,
                            int* label, float* mask01, float* scal) {
    int n = blockIdx.x * blockDim.x + threadIdx.x;
    int isbf = flags[0], ismb = flags[1];
    float m = 0.f;
    if (n < NN) {
        int lab = 0;
        for (int c = 0; c < CC; c++) {
            if (ldf(ytrue, n * CC + c, isbf) > 0.5f) { lab = c; break; }
        }
        label[n] = lab;
        int mv = ismb ? (int)((const unsigned char*)mask)[n] : ((const int*)mask)[n];
        m = mv ? 1.f : 0.f;
        mask01[n] = m;
    }
    __shared__ float sm[256];
    sm[threadIdx.x] = m; __syncthreads();
    for (int s = 128; s > 0; s >>= 1) {
        if (threadIdx.x < s) sm[threadIdx.x] += sm[threadIdx.x + s];
        __syncthreads();
    }
    if (threadIdx.x == 0) atomicAdd(&scal[0], sm[0]);
}

// ---------------- degree & norm ----------------
__global__ void deg_kernel(const int* dst, float* deg) {
    int e = blockIdx.x * blockDim.x + threadIdx.x;
    if (e < EE) atomicAdd(&deg[dst[e]], 1.0f);
}

__global__ void norm_kernel(float* deg) {
    int n = blockIdx.x * blockDim.x + threadIdx.x;
    if (n < NN) {
        float d = deg[n];
        if (d < 1.f) d = 1.f;
        deg[n] = rsqrtf(d);
    }
}

// ---------------- initial error + sigma numerator ----------------
__global__ void err_kernel(const void* ysoft, const int* flags, const int* label,
                           const float* mask01, float* err0, float* cur, float* scal) {
    int i = blockIdx.x * blockDim.x + threadIdx.x;
    int isbf = flags[0];
    float a = 0.f;
    if (i < NC) {
        int n = i >> 6, c = i & 63;
        float e = 0.f;
        if (mask01[n] != 0.f) {
            float t = (c == label[n]) ? 1.f : 0.f;
            e = t - ldf(ysoft, i, isbf);
        }
        err0[i] = e; cur[i] = e;
        a = fabsf(e);
    }
    __shared__ float sm[256];
    sm[threadIdx.x] = a; __syncthreads();
    for (int s = 128; s > 0; s >>= 1) {
        if (threadIdx.x < s) sm[threadIdx.x] += sm[threadIdx.x + s];
        __syncthreads();
    }
    if (threadIdx.x == 0) atomicAdd(&scal[1], sm[0]);
}

// ---------------- edge scatter: h[dst] += norm[src]*cur[src] ----------------
// 16 threads per edge, float4 per thread, 4 float atomics
__global__ void scatter_kernel(const int* __restrict__ src, const int* __restrict__ dst,
                               const float* __restrict__ norm,
                               const float4* __restrict__ cur4, float* __restrict__ h) {
    long tid = (long)blockIdx.x * blockDim.x + threadIdx.x;
    if (tid >= (long)EE * 16) return;
    int e = (int)(tid >> 4), q = (int)(tid & 15);
    int s = src[e], d = dst[e];
    float ns = norm[s];
    float4 v = cur4[s * 16 + q];
    float* hp = h + ((long)d * 64 + q * 4);
    atomicAdd(hp + 0, v.x * ns);
    atomicAdd(hp + 1, v.y * ns);
    atomicAdd(hp + 2, v.z * ns);
    atomicAdd(hp + 3, v.w * ns);
}

// ---------------- elementwise blend + clip (in-place on h) ----------------
__global__ void elem_kernel(const float* __restrict__ base, const float* __restrict__ norm,
                            float* __restrict__ h, float alpha, float lo, float hi) {
    int i = blockIdx.x * blockDim.x + threadIdx.x;
    if (i >= NC) return;
    int n = i >> 6;
    float v = (1.f - alpha) * base[i] + alpha * norm[n] * h[i];
    v = v < lo ? lo : (v > hi ? hi : v);
    h[i] = v;
}

// ---------------- per-row scale ----------------
__global__ void scale_kernel(const float* __restrict__ smv, const float* __restrict__ scal,
                             float* __restrict__ scale) {
    int n = blockIdx.x * blockDim.x + threadIdx.x;
    if (n >= NN) return;
    float rs = 0.f;
    for (int c = 0; c < CC; c++) rs += fabsf(smv[n * CC + c]);
    float sigma = scal[1] / scal[0];
    float s = sigma / rs;                 // +inf if rs==0 && sigma>0; NaN if both 0
    if (isinf(s) || s > 1000.f) s = 1.f;  // NaN passes through (matches ref)
    scale[n] = s;
}

// ---------------- y0 = where(mask, y_true, y_soft + scale*smoothed) ----------------
__global__ void y0_kernel(const void* ysoft, const int* flags, const int* label,
                          const float* mask01, const float* scale,
                          float* err0, float* cur /* holds smoothed, overwritten */) {
    int i = blockIdx.x * blockDim.x + threadIdx.x;
    if (i >= NC) return;
    int isbf = flags[0];
    int n = i >> 6, c = i & 63;
    float ys = ldf(ysoft, i, isbf);
    float r = ys + scale[n] * cur[i];
    if (isnan(r)) r = ys;
    float y = (mask01[n] != 0.f) ? ((c == label[n]) ? 1.f : 0.f) : r;
    err0[i] = y; cur[i] = y;
}

// ---------------- output convert ----------------
__global__ void out_kernel(const float* __restrict__ cur, const int* flags, void* out) {
    int i = blockIdx.x * blockDim.x + threadIdx.x;
    if (i >= NC) return;
    if (flags[0]) ((__hip_bfloat16*)out)[i] = __float2bfloat16(cur[i]);
    else          ((float*)out)[i] = cur[i];
}

extern "C" void kernel_launch(void* const* d_in, const int* in_sizes, int n_in,
                              void* d_out, int out_size, void* d_ws, size_t ws_size,
                              hipStream_t stream) {
    const void* ysoft = d_in[0];
    const void* ytrue = d_in[1];
    const int* src = (const int*)d_in[2];
    const int* dst = (const int*)d_in[3];
    const void* mask = d_in[4];

    char* ws = (char*)d_ws;
    int*   flags  = (int*)ws;            // 2 ints @ 0
    float* scal   = (float*)(ws + 64);   // [0]=numel, [1]=sum|err|
    size_t OFF_LABEL  = 1024;
    size_t OFF_MASK01 = OFF_LABEL  + (size_t)NN * sizeof(int);
    size_t OFF_NORM   = OFF_MASK01 + (size_t)NN * sizeof(float);
    size_t OFF_SCALE  = OFF_NORM   + (size_t)NN * sizeof(float);
    size_t OFF_BIG    = (OFF_SCALE + (size_t)NN * sizeof(float) + 255) & ~(size_t)255;
    int*   label  = (int*)(ws + OFF_LABEL);
    float* mask01 = (float*)(ws + OFF_MASK01);
    float* norm   = (float*)(ws + OFF_NORM);
    float* scale  = (float*)(ws + OFF_SCALE);
    float* err0   = (float*)(ws + OFF_BIG);
    float* bufA   = err0 + (size_t)NC;
    float* bufB   = bufA + (size_t)NC;

    // zero small region (flags, scal, norm accumulator)
    hipMemsetAsync(ws, 0, OFF_BIG, stream);

    detect_kernel<<<1024, 256, 0, stream>>>(ytrue, mask, flags);
    prep_kernel<<<(NN + 255) / 256, 256, 0, stream>>>(ytrue, mask, flags, label, mask01, scal);
    deg_kernel<<<(EE + 255) / 256, 256, 0, stream>>>(dst, norm);
    norm_kernel<<<(NN + 255) / 256, 256, 0, stream>>>(norm);
    err_kernel<<<(NC + 255) / 256, 256, 0, stream>>>(ysoft, flags, label, mask01, err0, bufA, scal);

    float* cur = bufA;
    float* nxt = bufB;
    const long scatter_threads = (long)EE * 16;
    const int scatter_blocks = (int)((scatter_threads + 255) / 256);

    // ---- correct phase: 10 layers, alpha=0.979, clip [-1, 1]
    for (int l = 0; l < 10; l++) {
        hipMemsetAsync(nxt, 0, (size_t)NC * sizeof(float), stream);
        scatter_kernel<<<scatter_blocks, 256, 0, stream>>>(src, dst, norm, (const float4*)cur, nxt);
        elem_kernel<<<(NC + 255) / 256, 256, 0, stream>>>(err0, norm, nxt, 0.979f, -1.f, 1.f);
        float* t = cur; cur = nxt; nxt = t;
    }

    // ---- rescale between phases
    scale_kernel<<<(NN + 255) / 256, 256, 0, stream>>>(cur, scal, scale);
    y0_kernel<<<(NC + 255) / 256, 256, 0, stream>>>(ysoft, flags, label, mask01, scale, err0, cur);

    // ---- smooth phase: 10 layers, alpha=0.756, clip [0, 1]
    for (int l = 0; l < 10; l++) {
        hipMemsetAsync(nxt, 0, (size_t)NC * sizeof(float), stream);
        scatter_kernel<<<scatter_blocks, 256, 0, stream>>>(src, dst, norm, (const float4*)cur, nxt);
        elem_kernel<<<(NC + 255) / 256, 256, 0, stream>>>(err0, norm, nxt, 0.756f, 0.f, 1.f);
        float* t = cur; cur = nxt; nxt = t;
    }

    out_kernel<<<(NC + 255) / 256, 256, 0, stream>>>(cur, flags, d_out);
}

// Round 2
// 3030.422 us; speedup vs baseline: 18.7939x; 18.7939x over previous
//
#include <hip/hip_runtime.h>
#include <hip/hip_bf16.h>

#define NN 100000
#define EE 3200000
#define CC 64
#define NC (NN*CC)
#define SCAN_BLOCKS 391   // ceil(NN/256)

// ---------------- dtype helpers ----------------
__device__ __forceinline__ float ldf(const void* p, int i, int isbf) {
    if (isbf) {
        unsigned int u = ((const unsigned short*)p)[i];
        return __uint_as_float(u << 16);
    }
    return ((const float*)p)[i];
}

// ---------------- detection ----------------
// flags[0]: 1 if float arrays are bf16, else fp32; flags[1]: 1 if mask is byte-bool
__global__ void detect_kernel(const void* ytrue, const void* mask, int* flags) {
    int tid = blockIdx.x * blockDim.x + threadIdx.x;
    int stride = gridDim.x * blockDim.x;
    const unsigned int* w = (const unsigned int*)ytrue;
    int nb = 0, nm = 0;
    for (int i = tid; i < NC / 2; i += stride)
        if ((w[i] & 0xFFFFu) == 0x3F80u) nb = 1;
    const unsigned char* mb = (const unsigned char*)mask;
    for (int i = tid; i < NN; i += stride)
        if ((i & 3) != 0 && mb[i] != 0) nm = 1;
    if (nb) atomicOr(&flags[0], 1);
    if (nm) atomicOr(&flags[1], 1);
}

// ---------------- prep: labels, mask01, numel ----------------
__global__ void prep_kernel(const void* ytrue, const void* mask, const int* flags,
                            int* label, float* mask01, float* scal) {
    int n = blockIdx.x * blockDim.x + threadIdx.x;
    int isbf = flags[0], ismb = flags[1];
    float m = 0.f;
    if (n < NN) {
        int lab = 0;
        for (int c = 0; c < CC; c++)
            if (ldf(ytrue, n * CC + c, isbf) > 0.5f) { lab = c; break; }
        label[n] = lab;
        int mv = ismb ? (int)((const unsigned char*)mask)[n] : ((const int*)mask)[n];
        m = mv ? 1.f : 0.f;
        mask01[n] = m;
    }
    __shared__ float sm[256];
    sm[threadIdx.x] = m; __syncthreads();
    for (int s = 128; s > 0; s >>= 1) {
        if (threadIdx.x < s) sm[threadIdx.x] += sm[threadIdx.x + s];
        __syncthreads();
    }
    if (threadIdx.x == 0) atomicAdd(&scal[0], sm[0]);
}

// ---------------- degree (int) ----------------
__global__ void deg_kernel(const int* __restrict__ dst, int* __restrict__ degi) {
    int e = blockIdx.x * blockDim.x + threadIdx.x;
    if (e < EE) atomicAdd(&degi[dst[e]], 1);
}

__global__ void norm_kernel(const int* __restrict__ degi, float* __restrict__ norm) {
    int n = blockIdx.x * blockDim.x + threadIdx.x;
    if (n < NN) {
        int d = degi[n]; if (d < 1) d = 1;
        norm[n] = rsqrtf((float)d);
    }
}

// ---------------- scan: chunk sums ----------------
__global__ void scan1_kernel(const int* __restrict__ degi, int* __restrict__ partials) {
    int t = threadIdx.x, i = blockIdx.x * 256 + t;
    __shared__ int sm[256];
    sm[t] = (i < NN) ? degi[i] : 0; __syncthreads();
    for (int s = 128; s > 0; s >>= 1) {
        if (t < s) sm[t] += sm[t + s];
        __syncthreads();
    }
    if (t == 0) partials[blockIdx.x] = sm[0];
}

// ---------------- scan: exclusive scan of partials (1 block, 512 thr) ----------------
__global__ void scan2_kernel(const int* __restrict__ partials, int* __restrict__ chunk_off) {
    int t = threadIdx.x;
    __shared__ int sm[512];
    int v = (t < SCAN_BLOCKS) ? partials[t] : 0;
    sm[t] = v; __syncthreads();
    for (int off = 1; off < 512; off <<= 1) {
        int x = (t >= off) ? sm[t - off] : 0;
        __syncthreads();
        sm[t] += x;
        __syncthreads();
    }
    chunk_off[t] = sm[t] - v;  // exclusive
}

// ---------------- scan: per-chunk exclusive scan -> row_ptr & cursor ----------------
__global__ void scan3_kernel(const int* __restrict__ degi, const int* __restrict__ chunk_off,
                             int* __restrict__ row_ptr, int* __restrict__ cursor) {
    int t = threadIdx.x, b = blockIdx.x, i = b * 256 + t;
    __shared__ int sm[256];
    int v = (i < NN) ? degi[i] : 0;
    sm[t] = v; __syncthreads();
    for (int off = 1; off < 256; off <<= 1) {
        int x = (t >= off) ? sm[t - off] : 0;
        __syncthreads();
        sm[t] += x;
        __syncthreads();
    }
    int base = chunk_off[b];
    if (i < NN) {
        int ex = base + sm[t] - v;
        row_ptr[i] = ex; cursor[i] = ex;
    }
    if (i == NN - 1) row_ptr[NN] = base + sm[t];
}

// ---------------- CSR fill ----------------
__global__ void fill_kernel(const int* __restrict__ src, const int* __restrict__ dst,
                            int* __restrict__ cursor, int* __restrict__ csr_src) {
    int e = blockIdx.x * blockDim.x + threadIdx.x;
    if (e < EE) {
        int pos = atomicAdd(&cursor[dst[e]], 1);
        csr_src[pos] = src[e];
    }
}

// ---------------- initial error + sigma numerator; writes base & curn ----------------
__global__ void err_kernel(const void* ysoft, const int* flags, const int* __restrict__ label,
                           const float* __restrict__ mask01, const float* __restrict__ norm,
                           float* __restrict__ base, float* __restrict__ curn, float* scal) {
    int i = blockIdx.x * blockDim.x + threadIdx.x;
    int isbf = flags[0];
    float a = 0.f;
    if (i < NC) {
        int n = i >> 6, c = i & 63;
        float e = 0.f;
        if (mask01[n] != 0.f) {
            float t = (c == label[n]) ? 1.f : 0.f;
            e = t - ldf(ysoft, i, isbf);
        }
        base[i] = e;
        curn[i] = e * norm[n];
        a = fabsf(e);
    }
    __shared__ float sm[256];
    sm[threadIdx.x] = a; __syncthreads();
    for (int s = 128; s > 0; s >>= 1) {
        if (threadIdx.x < s) sm[threadIdx.x] += sm[threadIdx.x + s];
        __syncthreads();
    }
    if (threadIdx.x == 0) atomicAdd(&scal[1], sm[0]);
}

// ---------------- pull-gather + blend + clip (one wave per dst node) ----------------
// out = store_norm ? clip(...)*norm : clip(...)
__global__ void gather_kernel(const int* __restrict__ row_ptr, const int* __restrict__ csr_src,
                              const float* __restrict__ curn, const float* __restrict__ base,
                              const float* __restrict__ norm, float* __restrict__ out,
                              float alpha, float lo, float hi, int store_norm) {
    int gt = blockIdx.x * blockDim.x + threadIdx.x;
    int node = gt >> 6, lane = gt & 63;
    if (node >= NN) return;
    int beg = row_ptr[node], end = row_ptr[node + 1];
    float acc0 = 0.f, acc1 = 0.f, acc2 = 0.f, acc3 = 0.f;
    for (int eb = beg; eb < end; eb += 64) {
        int ne = end - eb; if (ne > 64) ne = 64;
        int sv = (eb + lane < end) ? csr_src[eb + lane] : 0;
        int j = 0;
        for (; j + 3 < ne; j += 4) {
            int s0 = __shfl(sv, j, 64), s1 = __shfl(sv, j + 1, 64);
            int s2 = __shfl(sv, j + 2, 64), s3 = __shfl(sv, j + 3, 64);
            float v0 = curn[s0 * 64 + lane];
            float v1 = curn[s1 * 64 + lane];
            float v2 = curn[s2 * 64 + lane];
            float v3 = curn[s3 * 64 + lane];
            acc0 += v0; acc1 += v1; acc2 += v2; acc3 += v3;
        }
        for (; j < ne; j++) {
            int s0 = __shfl(sv, j, 64);
            acc0 += curn[s0 * 64 + lane];
        }
    }
    float nrm = norm[node];
    float v = (1.f - alpha) * base[node * 64 + lane] + alpha * nrm * (acc0 + acc1 + acc2 + acc3);
    v = v < lo ? lo : (v > hi ? hi : v);
    out[node * 64 + lane] = store_norm ? v * nrm : v;
}

// ---------------- per-row scale ----------------
__global__ void scale_kernel(const float* __restrict__ smv, const float* __restrict__ scal,
                             float* __restrict__ scale) {
    int n = blockIdx.x * blockDim.x + threadIdx.x;
    if (n >= NN) return;
    float rs = 0.f;
    for (int c = 0; c < CC; c++) rs += fabsf(smv[n * CC + c]);
    float sigma = scal[1] / scal[0];
    float s = sigma / rs;
    if (isinf(s) || s > 1000.f) s = 1.f;  // NaN falls through (matches ref)
    scale[n] = s;
}

// ---------------- y0 = where(mask, y_true, y_soft + scale*smoothed); writes base & curn ----
__global__ void y0_kernel(const void* ysoft, const int* flags, const int* __restrict__ label,
                          const float* __restrict__ mask01, const float* __restrict__ scale,
                          const float* __restrict__ norm,
                          float* __restrict__ base, float* __restrict__ cur_inout) {
    int i = blockIdx.x * blockDim.x + threadIdx.x;
    if (i >= NC) return;
    int isbf = flags[0];
    int n = i >> 6, c = i & 63;
    float ys = ldf(ysoft, i, isbf);
    float r = ys + scale[n] * cur_inout[i];
    if (isnan(r)) r = ys;
    float y = (mask01[n] != 0.f) ? ((c == label[n]) ? 1.f : 0.f) : r;
    base[i] = y;
    cur_inout[i] = y * norm[n];   // becomes curn for smooth phase (in-place)
}

// ---------------- output convert ----------------
__global__ void out_kernel(const float* __restrict__ cur, const int* flags, void* out) {
    int i = blockIdx.x * blockDim.x + threadIdx.x;
    if (i >= NC) return;
    if (flags[0]) ((__hip_bfloat16*)out)[i] = __float2bfloat16(cur[i]);
    else          ((float*)out)[i] = cur[i];
}

extern "C" void kernel_launch(void* const* d_in, const int* in_sizes, int n_in,
                              void* d_out, int out_size, void* d_ws, size_t ws_size,
                              hipStream_t stream) {
    const void* ysoft = d_in[0];
    const void* ytrue = d_in[1];
    const int* src = (const int*)d_in[2];
    const int* dst = (const int*)d_in[3];
    const void* mask = d_in[4];

    char* ws = (char*)d_ws;
    // small region (zeroed): flags, scal, partials, chunk_off, degi
    int*   flags     = (int*)ws;                  // @0, 2 ints
    float* scal      = (float*)(ws + 64);         // 2 floats
    int*   partials  = (int*)(ws + 4096);         // 512 ints
    int*   chunk_off = (int*)(ws + 8192);         // 512 ints
    int*   degi      = (int*)(ws + 16384);        // NN ints
    size_t ZERO_BYTES = 16384 + (size_t)NN * 4;

    size_t off = (ZERO_BYTES + 255) & ~(size_t)255;
    int*   label   = (int*)(ws + off);  off += (size_t)NN * 4;
    float* mask01  = (float*)(ws + off); off += (size_t)NN * 4;
    float* norm    = (float*)(ws + off); off += (size_t)NN * 4;
    float* scale   = (float*)(ws + off); off += (size_t)NN * 4;
    int*   row_ptr = (int*)(ws + off);  off += (size_t)(NN + 1) * 4;
    int*   cursor  = (int*)(ws + off);  off += (size_t)NN * 4;
    off = (off + 255) & ~(size_t)255;
    int*   csr_src = (int*)(ws + off);  off += (size_t)EE * 4;
    off = (off + 255) & ~(size_t)255;
    float* base    = (float*)(ws + off); off += (size_t)NC * 4;
    float* bufA    = (float*)(ws + off); off += (size_t)NC * 4;
    float* bufB    = (float*)(ws + off); off += (size_t)NC * 4;

    hipMemsetAsync(ws, 0, ZERO_BYTES, stream);

    detect_kernel<<<1024, 256, 0, stream>>>(ytrue, mask, flags);
    prep_kernel<<<(NN + 255) / 256, 256, 0, stream>>>(ytrue, mask, flags, label, mask01, scal);
    deg_kernel<<<(EE + 255) / 256, 256, 0, stream>>>(dst, degi);
    norm_kernel<<<(NN + 255) / 256, 256, 0, stream>>>(degi, norm);
    scan1_kernel<<<SCAN_BLOCKS, 256, 0, stream>>>(degi, partials);
    scan2_kernel<<<1, 512, 0, stream>>>(partials, chunk_off);
    scan3_kernel<<<SCAN_BLOCKS, 256, 0, stream>>>(degi, chunk_off, row_ptr, cursor);
    fill_kernel<<<(EE + 255) / 256, 256, 0, stream>>>(src, dst, cursor, csr_src);
    err_kernel<<<(NC + 255) / 256, 256, 0, stream>>>(ysoft, flags, label, mask01, norm, base, bufA, scal);

    const int gather_blocks = (NN * 64 + 255) / 256;

    // ---- correct phase: 10 layers, alpha=0.979, clip [-1,1]
    float* cur = bufA; float* nxt = bufB;
    for (int l = 0; l < 10; l++) {
        int store_norm = (l < 9) ? 1 : 0;   // last layer stores unnormalized
        gather_kernel<<<gather_blocks, 256, 0, stream>>>(row_ptr, csr_src, cur, base, norm, nxt,
                                                         0.979f, -1.f, 1.f, store_norm);
        float* t = cur; cur = nxt; nxt = t;
    }
    // cur now holds smoothed_error (unnormalized, clipped)

    scale_kernel<<<(NN + 255) / 256, 256, 0, stream>>>(cur, scal, scale);
    y0_kernel<<<(NC + 255) / 256, 256, 0, stream>>>(ysoft, flags, label, mask01, scale, norm, base, cur);
    // cur now holds y0*norm (curn for smooth phase); base holds y0

    // ---- smooth phase: 10 layers, alpha=0.756, clip [0,1]
    for (int l = 0; l < 10; l++) {
        int store_norm = (l < 9) ? 1 : 0;
        gather_kernel<<<gather_blocks, 256, 0, stream>>>(row_ptr, csr_src, cur, base, norm, nxt,
                                                         0.756f, 0.f, 1.f, store_norm);
        float* t = cur; cur = nxt; nxt = t;
    }

    out_kernel<<<(NC + 255) / 256, 256, 0, stream>>>(cur, flags, d_out);
}

// Round 3
// 2712.440 us; speedup vs baseline: 20.9971x; 1.1172x over previous
//
#include <hip/hip_runtime.h>
#include <hip/hip_bf16.h>

#define NN 100000
#define EE 3200000
#define CC 64
#define NC (NN*CC)
#define SCAN_BLOCKS 391        // ceil(NN/256)
#define ERR_BLOCKS 6250        // NC/4/256

// ---------------- dtype helpers ----------------
__device__ __forceinline__ float ldf(const void* p, long i, int isbf) {
    if (isbf) {
        unsigned int u = ((const unsigned short*)p)[i];
        return __uint_as_float(u << 16);
    }
    return ((const float*)p)[i];
}

__device__ __forceinline__ float wave_sum(float a) {
    for (int m = 1; m < 64; m <<= 1) a += __shfl_xor(a, m, 64);
    return a;
}

// ---------------- detection (1 block, sampled) ----------------
// flags[0]: float arrays are bf16; flags[1]: mask is byte-bool
__global__ void detect_kernel(const void* ytrue, const void* mask, int* flags) {
    int t = threadIdx.x;
    const unsigned int* w = (const unsigned int*)ytrue;
    int nb = 0, nm = 0;
    // 16384 words covers >=256 one-hot rows in bf16; fp32 one-hot words never have low16==0x3F80
    for (int i = t; i < 16384; i += 256)
        if ((w[i] & 0xFFFFu) == 0x3F80u) nb = 1;
    const unsigned char* mb = (const unsigned char*)mask;
    for (int i = t; i < 4096; i += 256)
        if ((i & 3) != 0 && mb[i] != 0) nm = 1;
    if (nb) atomicOr(&flags[0], 1);
    if (nm) atomicOr(&flags[1], 1);
}

// ---------------- prep: wave per node; label via ballot ----------------
__global__ void prep_kernel(const void* ytrue, const void* mask, const int* flags,
                            int* __restrict__ label, float* __restrict__ mask01) {
    int gt = blockIdx.x * blockDim.x + threadIdx.x;
    int node = gt >> 6, lane = gt & 63;
    if (node >= NN) return;
    int isbf = flags[0];
    float tv = ldf(ytrue, (long)node * CC + lane, isbf);
    unsigned long long b = __ballot(tv > 0.5f);
    if (lane == 0) {
        label[node] = (b == 0ull) ? 0 : (__ffsll((long long)b) - 1);
        int mv = flags[1] ? (int)((const unsigned char*)mask)[node] : ((const int*)mask)[node];
        mask01[node] = mv ? 1.f : 0.f;
    }
}

// ---------------- degree (int) ----------------
__global__ void deg_kernel(const int* __restrict__ dst, int* __restrict__ degi) {
    int e = blockIdx.x * blockDim.x + threadIdx.x;
    if (e < EE) atomicAdd(&degi[dst[e]], 1);
}

__global__ void norm_kernel(const int* __restrict__ degi, float* __restrict__ norm) {
    int n = blockIdx.x * blockDim.x + threadIdx.x;
    if (n < NN) {
        int d = degi[n]; if (d < 1) d = 1;
        norm[n] = rsqrtf((float)d);
    }
}

// ---------------- scan: chunk sums ----------------
__global__ void scan1_kernel(const int* __restrict__ degi, int* __restrict__ partials) {
    int t = threadIdx.x, i = blockIdx.x * 256 + t;
    __shared__ int sm[256];
    sm[t] = (i < NN) ? degi[i] : 0; __syncthreads();
    for (int s = 128; s > 0; s >>= 1) {
        if (t < s) sm[t] += sm[t + s];
        __syncthreads();
    }
    if (t == 0) partials[blockIdx.x] = sm[0];
}

__global__ void scan2_kernel(const int* __restrict__ partials, int* __restrict__ chunk_off) {
    int t = threadIdx.x;
    __shared__ int sm[512];
    int v = (t < SCAN_BLOCKS) ? partials[t] : 0;
    sm[t] = v; __syncthreads();
    for (int off = 1; off < 512; off <<= 1) {
        int x = (t >= off) ? sm[t - off] : 0;
        __syncthreads();
        sm[t] += x;
        __syncthreads();
    }
    chunk_off[t] = sm[t] - v;  // exclusive
}

__global__ void scan3_kernel(const int* __restrict__ degi, const int* __restrict__ chunk_off,
                             int* __restrict__ row_ptr, int* __restrict__ cursor) {
    int t = threadIdx.x, b = blockIdx.x, i = b * 256 + t;
    __shared__ int sm[256];
    int v = (i < NN) ? degi[i] : 0;
    sm[t] = v; __syncthreads();
    for (int off = 1; off < 256; off <<= 1) {
        int x = (t >= off) ? sm[t - off] : 0;
        __syncthreads();
        sm[t] += x;
        __syncthreads();
    }
    int base = chunk_off[b];
    if (i < NN) {
        int ex = base + sm[t] - v;
        row_ptr[i] = ex; cursor[i] = ex;
    }
    if (i == NN - 1) row_ptr[NN] = base + sm[t];
}

// ---------------- CSR fill ----------------
__global__ void fill_kernel(const int* __restrict__ src, const int* __restrict__ dst,
                            int* __restrict__ cursor, int* __restrict__ csr_src) {
    int e = blockIdx.x * blockDim.x + threadIdx.x;
    if (e < EE) {
        int pos = atomicAdd(&cursor[dst[e]], 1);
        csr_src[pos] = src[e];
    }
}

// ---------------- initial error (x4 vectorized) + per-block |e| partials ----------------
__global__ void err_kernel(const void* ysoft, const int* flags, const int* __restrict__ label,
                           const float* __restrict__ mask01, const float* __restrict__ norm,
                           float* __restrict__ base, float* __restrict__ curn,
                           float* __restrict__ err_part) {
    int i4 = blockIdx.x * 256 + threadIdx.x;     // float4 index, i4 < NC/4
    int node = i4 >> 4;
    int isbf = flags[0];
    float m = mask01[node];
    int lab = label[node];
    float nrm = norm[node];
    int c0 = (i4 & 15) * 4;
    float4 e;
    if (isbf) {
        ushort4 u = ((const ushort4*)ysoft)[i4];
        e.x = __uint_as_float((unsigned)u.x << 16);
        e.y = __uint_as_float((unsigned)u.y << 16);
        e.z = __uint_as_float((unsigned)u.z << 16);
        e.w = __uint_as_float((unsigned)u.w << 16);
    } else {
        e = ((const float4*)ysoft)[i4];
    }
    e.x = (m != 0.f) ? ((c0 + 0 == lab) ? 1.f : 0.f) - e.x : 0.f;
    e.y = (m != 0.f) ? ((c0 + 1 == lab) ? 1.f : 0.f) - e.y : 0.f;
    e.z = (m != 0.f) ? ((c0 + 2 == lab) ? 1.f : 0.f) - e.z : 0.f;
    e.w = (m != 0.f) ? ((c0 + 3 == lab) ? 1.f : 0.f) - e.w : 0.f;
    ((float4*)base)[i4] = e;
    float4 en = make_float4(e.x * nrm, e.y * nrm, e.z * nrm, e.w * nrm);
    ((float4*)curn)[i4] = en;
    float a = fabsf(e.x) + fabsf(e.y) + fabsf(e.z) + fabsf(e.w);
    a = wave_sum(a);
    __shared__ float sm[4];
    if ((threadIdx.x & 63) == 0) sm[threadIdx.x >> 6] = a;
    __syncthreads();
    if (threadIdx.x == 0) err_part[blockIdx.x] = sm[0] + sm[1] + sm[2] + sm[3];
}

// ---------------- single-block reduce: scal[0]=numel, scal[1]=sum|err| ----------------
__global__ void reduce_kernel(const float* __restrict__ mask01,
                              const float* __restrict__ err_part, float* __restrict__ scal) {
    int t = threadIdx.x;
    float s0 = 0.f, s1 = 0.f;
    for (int i = t; i < NN; i += 1024) s0 += mask01[i];
    for (int i = t; i < ERR_BLOCKS; i += 1024) s1 += err_part[i];
    __shared__ float a0[1024], a1[1024];
    a0[t] = s0; a1[t] = s1; __syncthreads();
    for (int s = 512; s > 0; s >>= 1) {
        if (t < s) { a0[t] += a0[t + s]; a1[t] += a1[t + s]; }
        __syncthreads();
    }
    if (t == 0) { scal[0] = a0[0]; scal[1] = a1[0]; }
}

// ---------------- pull-gather + blend + clip (one wave per dst node) ----------------
// mode 0: store v*nrm (next curn)
// mode 1: store v, plus rowsum[node] = sum|v| (last correct layer)
// mode 3: final — write to d_out per dtype flag
__global__ void gather_kernel(const int* __restrict__ row_ptr, const int* __restrict__ csr_src,
                              const float* __restrict__ curn, const float* __restrict__ base,
                              const float* __restrict__ norm, float* __restrict__ out,
                              float* __restrict__ rowsum, const int* flags,
                              float alpha, float lo, float hi, int mode) {
    int gt = blockIdx.x * blockDim.x + threadIdx.x;
    int node = gt >> 6, lane = gt & 63;
    if (node >= NN) return;
    int beg = row_ptr[node], end = row_ptr[node + 1];
    float acc0 = 0.f, acc1 = 0.f, acc2 = 0.f, acc3 = 0.f;
    for (int eb = beg; eb < end; eb += 64) {
        int ne = end - eb; if (ne > 64) ne = 64;
        int sv = (eb + lane < end) ? csr_src[eb + lane] : 0;
        int j = 0;
        for (; j + 7 < ne; j += 8) {
            int s0 = __shfl(sv, j, 64),     s1 = __shfl(sv, j + 1, 64);
            int s2 = __shfl(sv, j + 2, 64), s3 = __shfl(sv, j + 3, 64);
            int s4 = __shfl(sv, j + 4, 64), s5 = __shfl(sv, j + 5, 64);
            int s6 = __shfl(sv, j + 6, 64), s7 = __shfl(sv, j + 7, 64);
            float v0 = curn[(long)s0 * 64 + lane];
            float v1 = curn[(long)s1 * 64 + lane];
            float v2 = curn[(long)s2 * 64 + lane];
            float v3 = curn[(long)s3 * 64 + lane];
            float v4 = curn[(long)s4 * 64 + lane];
            float v5 = curn[(long)s5 * 64 + lane];
            float v6 = curn[(long)s6 * 64 + lane];
            float v7 = curn[(long)s7 * 64 + lane];
            acc0 += v0 + v4; acc1 += v1 + v5; acc2 += v2 + v6; acc3 += v3 + v7;
        }
        for (; j < ne; j++) {
            int s0 = __shfl(sv, j, 64);
            acc0 += curn[(long)s0 * 64 + lane];
        }
    }
    float nrm = norm[node];
    long idx = (long)node * 64 + lane;
    float v = (1.f - alpha) * base[idx] + alpha * nrm * (acc0 + acc1 + acc2 + acc3);
    v = v < lo ? lo : (v > hi ? hi : v);
    if (mode == 0) {
        out[idx] = v * nrm;
    } else if (mode == 1) {
        out[idx] = v;
        float rs = wave_sum(fabsf(v));
        if (lane == 0) rowsum[node] = rs;
    } else {
        if (flags[0]) ((__hip_bfloat16*)out)[idx] = __float2bfloat16(v);
        else          ((float*)out)[idx] = v;
    }
}

// ---------------- per-node scale from fused rowsum ----------------
__global__ void scale_kernel(const float* __restrict__ rowsum, const float* __restrict__ scal,
                             float* __restrict__ scale) {
    int n = blockIdx.x * blockDim.x + threadIdx.x;
    if (n >= NN) return;
    float sigma = scal[1] / scal[0];
    float s = sigma / rowsum[n];
    if (isinf(s) || s > 1000.f) s = 1.f;  // NaN falls through (matches ref)
    scale[n] = s;
}

// ---------------- y0 (x4 vectorized): base=y0, cur<-y0*norm in place ----------------
__global__ void y0_kernel(const void* ysoft, const int* flags, const int* __restrict__ label,
                          const float* __restrict__ mask01, const float* __restrict__ scale,
                          const float* __restrict__ norm,
                          float* __restrict__ base, float* __restrict__ cur_inout) {
    int i4 = blockIdx.x * 256 + threadIdx.x;
    int node = i4 >> 4;
    int isbf = flags[0];
    float m = mask01[node];
    int lab = label[node];
    float nrm = norm[node], sc = scale[node];
    int c0 = (i4 & 15) * 4;
    float4 ys;
    if (isbf) {
        ushort4 u = ((const ushort4*)ysoft)[i4];
        ys.x = __uint_as_float((unsigned)u.x << 16);
        ys.y = __uint_as_float((unsigned)u.y << 16);
        ys.z = __uint_as_float((unsigned)u.z << 16);
        ys.w = __uint_as_float((unsigned)u.w << 16);
    } else {
        ys = ((const float4*)ysoft)[i4];
    }
    float4 sm = ((const float4*)cur_inout)[i4];
    float4 y;
    float rx = ys.x + sc * sm.x; if (isnan(rx)) rx = ys.x;
    float ry = ys.y + sc * sm.y; if (isnan(ry)) ry = ys.y;
    float rz = ys.z + sc * sm.z; if (isnan(rz)) rz = ys.z;
    float rw = ys.w + sc * sm.w; if (isnan(rw)) rw = ys.w;
    y.x = (m != 0.f) ? ((c0 + 0 == lab) ? 1.f : 0.f) : rx;
    y.y = (m != 0.f) ? ((c0 + 1 == lab) ? 1.f : 0.f) : ry;
    y.z = (m != 0.f) ? ((c0 + 2 == lab) ? 1.f : 0.f) : rz;
    y.w = (m != 0.f) ? ((c0 + 3 == lab) ? 1.f : 0.f) : rw;
    ((float4*)base)[i4] = y;
    ((float4*)cur_inout)[i4] = make_float4(y.x * nrm, y.y * nrm, y.z * nrm, y.w * nrm);
}

extern "C" void kernel_launch(void* const* d_in, const int* in_sizes, int n_in,
                              void* d_out, int out_size, void* d_ws, size_t ws_size,
                              hipStream_t stream) {
    const void* ysoft = d_in[0];
    const void* ytrue = d_in[1];
    const int* src = (const int*)d_in[2];
    const int* dst = (const int*)d_in[3];
    const void* mask = d_in[4];

    char* ws = (char*)d_ws;
    int*   flags     = (int*)ws;                   // zeroed
    float* scal      = (float*)(ws + 64);
    int*   partials  = (int*)(ws + 4096);          // 512 ints
    int*   chunk_off = (int*)(ws + 8192);          // 512 ints
    float* err_part  = (float*)(ws + 12288);       // ERR_BLOCKS floats (25 KB)
    int*   degi      = (int*)(ws + 40960);         // NN ints, zeroed
    size_t ZERO_BYTES = 40960 + (size_t)NN * 4;

    size_t off = (ZERO_BYTES + 255) & ~(size_t)255;
    int*   label   = (int*)(ws + off);   off += (size_t)NN * 4;
    float* mask01  = (float*)(ws + off); off += (size_t)NN * 4;
    float* norm    = (float*)(ws + off); off += (size_t)NN * 4;
    float* scale   = (float*)(ws + off); off += (size_t)NN * 4;
    float* rowsum  = (float*)(ws + off); off += (size_t)NN * 4;
    int*   row_ptr = (int*)(ws + off);   off += (size_t)(NN + 1) * 4;
    int*   cursor  = (int*)(ws + off);   off += (size_t)NN * 4;
    off = (off + 255) & ~(size_t)255;
    int*   csr_src = (int*)(ws + off);   off += (size_t)EE * 4;
    off = (off + 255) & ~(size_t)255;
    float* base    = (float*)(ws + off); off += (size_t)NC * 4;
    float* bufA    = (float*)(ws + off); off += (size_t)NC * 4;
    float* bufB    = (float*)(ws + off); off += (size_t)NC * 4;

    hipMemsetAsync(ws, 0, ZERO_BYTES, stream);

    detect_kernel<<<1, 256, 0, stream>>>(ytrue, mask, flags);
    prep_kernel<<<(NN * 64 + 255) / 256, 256, 0, stream>>>(ytrue, mask, flags, label, mask01);
    deg_kernel<<<(EE + 255) / 256, 256, 0, stream>>>(dst, degi);
    norm_kernel<<<(NN + 255) / 256, 256, 0, stream>>>(degi, norm);
    scan1_kernel<<<SCAN_BLOCKS, 256, 0, stream>>>(degi, partials);
    scan2_kernel<<<1, 512, 0, stream>>>(partials, chunk_off);
    scan3_kernel<<<SCAN_BLOCKS, 256, 0, stream>>>(degi, chunk_off, row_ptr, cursor);
    fill_kernel<<<(EE + 255) / 256, 256, 0, stream>>>(src, dst, cursor, csr_src);
    err_kernel<<<ERR_BLOCKS, 256, 0, stream>>>(ysoft, flags, label, mask01, norm, base, bufA, err_part);
    reduce_kernel<<<1, 1024, 0, stream>>>(mask01, err_part, scal);

    const int gather_blocks = (NN * 64 + 255) / 256;

    // ---- correct phase: 10 layers, alpha=0.979, clip [-1,1]
    float* cur = bufA; float* nxt = bufB;
    for (int l = 0; l < 10; l++) {
        int mode = (l < 9) ? 0 : 1;  // last layer: store unnormalized + fused rowsum
        gather_kernel<<<gather_blocks, 256, 0, stream>>>(row_ptr, csr_src, cur, base, norm, nxt,
                                                         rowsum, flags, 0.979f, -1.f, 1.f, mode);
        float* t = cur; cur = nxt; nxt = t;
    }

    scale_kernel<<<(NN + 255) / 256, 256, 0, stream>>>(rowsum, scal, scale);
    y0_kernel<<<ERR_BLOCKS, 256, 0, stream>>>(ysoft, flags, label, mask01, scale, norm, base, cur);

    // ---- smooth phase: 10 layers, alpha=0.756, clip [0,1]; last writes d_out
    for (int l = 0; l < 10; l++) {
        int mode = (l < 9) ? 0 : 3;
        float* o = (l < 9) ? nxt : (float*)d_out;
        gather_kernel<<<gather_blocks, 256, 0, stream>>>(row_ptr, csr_src, cur, base, norm, o,
                                                         rowsum, flags, 0.756f, 0.f, 1.f, mode);
        float* t = cur; cur = nxt; nxt = t;
    }
}

// Round 4
// 1790.115 us; speedup vs baseline: 31.8155x; 1.5152x over previous
//
#include <hip/hip_runtime.h>
#include <hip/hip_bf16.h>

#define NN 100000
#define EE 3200000
#define CC 64
#define NC (NN*CC)
#define SCAN_BLOCKS 391        // ceil(NN/256)
#define ERR_BLOCKS 6250        // NC/4/256

// ---------------- helpers ----------------
__device__ __forceinline__ float ldf(const void* p, long i, int isbf) {
    if (isbf) {
        unsigned int u = ((const unsigned short*)p)[i];
        return __uint_as_float(u << 16);
    }
    return ((const float*)p)[i];
}

__device__ __forceinline__ float wave_sum(float a) {
    for (int m = 1; m < 64; m <<= 1) a += __shfl_xor(a, m, 64);
    return a;
}

// round-to-nearest-even bf16 pack of (a -> low16, b -> high16)
__device__ __forceinline__ unsigned pack_bf16(float a, float b) {
    unsigned ua = __float_as_uint(a); ua = (ua + 0x7FFFu + ((ua >> 16) & 1u)) >> 16;
    unsigned ub = __float_as_uint(b); ub = (ub + 0x7FFFu + ((ub >> 16) & 1u)) >> 16;
    return ua | (ub << 16);
}

// ---------------- detection (1 block, sampled) ----------------
__global__ void detect_kernel(const void* ytrue, const void* mask, int* flags) {
    int t = threadIdx.x;
    const unsigned int* w = (const unsigned int*)ytrue;
    int nb = 0, nm = 0;
    for (int i = t; i < 16384; i += 256)
        if ((w[i] & 0xFFFFu) == 0x3F80u) nb = 1;   // bf16 1.0 at even class
    const unsigned char* mb = (const unsigned char*)mask;
    for (int i = t; i < 4096; i += 256)
        if ((i & 3) != 0 && mb[i] != 0) nm = 1;
    if (nb) atomicOr(&flags[0], 1);
    if (nm) atomicOr(&flags[1], 1);
}

// ---------------- prep: wave per node; label via ballot ----------------
__global__ void prep_kernel(const void* ytrue, const void* mask, const int* flags,
                            int* __restrict__ label, float* __restrict__ mask01) {
    int gt = blockIdx.x * blockDim.x + threadIdx.x;
    int node = gt >> 6, lane = gt & 63;
    if (node >= NN) return;
    int isbf = flags[0];
    float tv = ldf(ytrue, (long)node * CC + lane, isbf);
    unsigned long long b = __ballot(tv > 0.5f);
    if (lane == 0) {
        label[node] = (b == 0ull) ? 0 : (__ffsll((long long)b) - 1);
        int mv = flags[1] ? (int)((const unsigned char*)mask)[node] : ((const int*)mask)[node];
        mask01[node] = mv ? 1.f : 0.f;
    }
}

// ---------------- degree ----------------
__global__ void deg_kernel(const int* __restrict__ dst, int* __restrict__ degi) {
    int e = blockIdx.x * blockDim.x + threadIdx.x;
    if (e < EE) atomicAdd(&degi[dst[e]], 1);
}

__global__ void norm_kernel(const int* __restrict__ degi, float* __restrict__ norm) {
    int n = blockIdx.x * blockDim.x + threadIdx.x;
    if (n < NN) {
        int d = degi[n]; if (d < 1) d = 1;
        norm[n] = rsqrtf((float)d);
    }
}

// ---------------- scans ----------------
__global__ void scan1_kernel(const int* __restrict__ degi, int* __restrict__ partials) {
    int t = threadIdx.x, i = blockIdx.x * 256 + t;
    __shared__ int sm[256];
    sm[t] = (i < NN) ? degi[i] : 0; __syncthreads();
    for (int s = 128; s > 0; s >>= 1) {
        if (t < s) sm[t] += sm[t + s];
        __syncthreads();
    }
    if (t == 0) partials[blockIdx.x] = sm[0];
}

__global__ void scan2_kernel(const int* __restrict__ partials, int* __restrict__ chunk_off) {
    int t = threadIdx.x;
    __shared__ int sm[512];
    int v = (t < SCAN_BLOCKS) ? partials[t] : 0;
    sm[t] = v; __syncthreads();
    for (int off = 1; off < 512; off <<= 1) {
        int x = (t >= off) ? sm[t - off] : 0;
        __syncthreads();
        sm[t] += x;
        __syncthreads();
    }
    chunk_off[t] = sm[t] - v;
}

__global__ void scan3_kernel(const int* __restrict__ degi, const int* __restrict__ chunk_off,
                             int* __restrict__ row_ptr, int* __restrict__ cursor) {
    int t = threadIdx.x, b = blockIdx.x, i = b * 256 + t;
    __shared__ int sm[256];
    int v = (i < NN) ? degi[i] : 0;
    sm[t] = v; __syncthreads();
    for (int off = 1; off < 256; off <<= 1) {
        int x = (t >= off) ? sm[t - off] : 0;
        __syncthreads();
        sm[t] += x;
        __syncthreads();
    }
    int base = chunk_off[b];
    if (i < NN) {
        int ex = base + sm[t] - v;
        row_ptr[i] = ex; cursor[i] = ex;
    }
    if (i == NN - 1) row_ptr[NN] = base + sm[t];
}

// ---------------- CSR fill ----------------
__global__ void fill_kernel(const int* __restrict__ src, const int* __restrict__ dst,
                            int* __restrict__ cursor, int* __restrict__ csr_src) {
    int e = blockIdx.x * blockDim.x + threadIdx.x;
    if (e < EE) {
        int pos = atomicAdd(&cursor[dst[e]], 1);
        csr_src[pos] = src[e];
    }
}

// ---------------- initial error: base fp32, curn bf16-packed, |e| partials ----------------
__global__ void err_kernel(const void* ysoft, const int* flags, const int* __restrict__ label,
                           const float* __restrict__ mask01, const float* __restrict__ norm,
                           float* __restrict__ base, unsigned* __restrict__ curn,
                           float* __restrict__ err_part) {
    int i4 = blockIdx.x * 256 + threadIdx.x;     // float4 index
    int node = i4 >> 4;
    int isbf = flags[0];
    float m = mask01[node];
    int lab = label[node];
    float nrm = norm[node];
    int c0 = (i4 & 15) * 4;
    float4 e;
    if (isbf) {
        ushort4 u = ((const ushort4*)ysoft)[i4];
        e.x = __uint_as_float((unsigned)u.x << 16);
        e.y = __uint_as_float((unsigned)u.y << 16);
        e.z = __uint_as_float((unsigned)u.z << 16);
        e.w = __uint_as_float((unsigned)u.w << 16);
    } else {
        e = ((const float4*)ysoft)[i4];
    }
    e.x = (m != 0.f) ? ((c0 + 0 == lab) ? 1.f : 0.f) - e.x : 0.f;
    e.y = (m != 0.f) ? ((c0 + 1 == lab) ? 1.f : 0.f) - e.y : 0.f;
    e.z = (m != 0.f) ? ((c0 + 2 == lab) ? 1.f : 0.f) - e.z : 0.f;
    e.w = (m != 0.f) ? ((c0 + 3 == lab) ? 1.f : 0.f) - e.w : 0.f;
    ((float4*)base)[i4] = e;
    ((uint2*)curn)[i4] = make_uint2(pack_bf16(e.x * nrm, e.y * nrm),
                                    pack_bf16(e.z * nrm, e.w * nrm));
    float a = fabsf(e.x) + fabsf(e.y) + fabsf(e.z) + fabsf(e.w);
    a = wave_sum(a);
    __shared__ float sm[4];
    if ((threadIdx.x & 63) == 0) sm[threadIdx.x >> 6] = a;
    __syncthreads();
    if (threadIdx.x == 0) err_part[blockIdx.x] = sm[0] + sm[1] + sm[2] + sm[3];
}

// ---------------- single-block reduce: scal[0]=numel, scal[1]=sum|err| ----------------
__global__ void reduce_kernel(const float* __restrict__ mask01,
                              const float* __restrict__ err_part, float* __restrict__ scal) {
    int t = threadIdx.x;
    float s0 = 0.f, s1 = 0.f;
    for (int i = t; i < NN; i += 1024) s0 += mask01[i];
    for (int i = t; i < ERR_BLOCKS; i += 1024) s1 += err_part[i];
    __shared__ float a0[1024], a1[1024];
    a0[t] = s0; a1[t] = s1; __syncthreads();
    for (int s = 512; s > 0; s >>= 1) {
        if (t < s) { a0[t] += a0[t + s]; a1[t] += a1[t + s]; }
        __syncthreads();
    }
    if (t == 0) { scal[0] = a0[0]; scal[1] = a1[0]; }
}

// ---------------- pull-gather, bf16 state (wave per node; 2 edges per step) ----------------
// mode 0: store pack_bf16(v*nrm) -> next curn
// mode 1: store fp32 v (float2) + rowsum[node]=sum|v|
// mode 3: final -> d_out per dtype flag
__global__ void gather_kernel(const int* __restrict__ row_ptr, const int* __restrict__ csr_src,
                              const unsigned* __restrict__ curn, const float* __restrict__ base,
                              const float* __restrict__ norm, void* __restrict__ out,
                              float* __restrict__ rowsum, const int* flags,
                              float alpha, float lo, float hi, int mode) {
    int gt = blockIdx.x * blockDim.x + threadIdx.x;
    int node = gt >> 6, lane = gt & 63;
    if (node >= NN) return;
    int hl = lane & 31;          // half-lane: class pair index
    int half = lane >> 5;        // 0 -> even edge, 1 -> odd edge
    int beg = row_ptr[node], end = row_ptr[node + 1];
    float acc0 = 0.f, acc1 = 0.f, acc2 = 0.f, acc3 = 0.f;
    for (int eb = beg; eb < end; eb += 64) {
        int ne = end - eb; if (ne > 64) ne = 64;
        int sv = (eb + lane < end) ? csr_src[eb + lane] : 0;
        int j = 0;
        for (; j + 7 < ne; j += 8) {
            int sA = __shfl(sv, j + 0 + half, 64);
            int sB = __shfl(sv, j + 2 + half, 64);
            int sC = __shfl(sv, j + 4 + half, 64);
            int sD = __shfl(sv, j + 6 + half, 64);
            unsigned wA = curn[(long)sA * 32 + hl];
            unsigned wB = curn[(long)sB * 32 + hl];
            unsigned wC = curn[(long)sC * 32 + hl];
            unsigned wD = curn[(long)sD * 32 + hl];
            acc0 += __uint_as_float(wA << 16) + __uint_as_float(wC << 16);
            acc1 += __uint_as_float(wA & 0xFFFF0000u) + __uint_as_float(wC & 0xFFFF0000u);
            acc2 += __uint_as_float(wB << 16) + __uint_as_float(wD << 16);
            acc3 += __uint_as_float(wB & 0xFFFF0000u) + __uint_as_float(wD & 0xFFFF0000u);
        }
        for (; j < ne; j += 2) {
            int jj = j + half;
            float wt = (jj < ne) ? 1.f : 0.f;
            int s = __shfl(sv, (jj < ne) ? jj : j, 64);
            unsigned w = curn[(long)s * 32 + hl];
            acc0 += wt * __uint_as_float(w << 16);
            acc1 += wt * __uint_as_float(w & 0xFFFF0000u);
        }
    }
    acc0 += acc2; acc1 += acc3;
    // fold odd-edge half into even half (and vice versa): both halves -> full sums
    acc0 += __shfl_xor(acc0, 32, 64);
    acc1 += __shfl_xor(acc1, 32, 64);

    float nrm = norm[node];
    long i2 = (long)node * 32 + hl;
    float2 b2 = ((const float2*)base)[i2];
    float v0 = (1.f - alpha) * b2.x + alpha * nrm * acc0;
    float v1 = (1.f - alpha) * b2.y + alpha * nrm * acc1;
    v0 = v0 < lo ? lo : (v0 > hi ? hi : v0);
    v1 = v1 < lo ? lo : (v1 > hi ? hi : v1);

    if (mode == 1) {
        float contrib = (lane < 32) ? (fabsf(v0) + fabsf(v1)) : 0.f;
        float rs = wave_sum(contrib);
        if (lane == 0) rowsum[node] = rs;
        if (lane < 32) ((float2*)out)[i2] = make_float2(v0, v1);
    } else if (mode == 0) {
        if (lane < 32) ((unsigned*)out)[i2] = pack_bf16(v0 * nrm, v1 * nrm);
    } else {
        if (lane < 32) {
            if (flags[0]) ((unsigned*)out)[i2] = pack_bf16(v0, v1);
            else          ((float2*)out)[i2] = make_float2(v0, v1);
        }
    }
}

// ---------------- per-node scale ----------------
__global__ void scale_kernel(const float* __restrict__ rowsum, const float* __restrict__ scal,
                             float* __restrict__ scale) {
    int n = blockIdx.x * blockDim.x + threadIdx.x;
    if (n >= NN) return;
    float sigma = scal[1] / scal[0];
    float s = sigma / rowsum[n];
    if (isinf(s) || s > 1000.f) s = 1.f;  // NaN falls through (matches ref)
    scale[n] = s;
}

// ---------------- y0: base=y0 fp32, curn=bf16(y0*norm) ----------------
__global__ void y0_kernel(const void* ysoft, const int* flags, const int* __restrict__ label,
                          const float* __restrict__ mask01, const float* __restrict__ scale,
                          const float* __restrict__ norm, const float* __restrict__ smoothed,
                          float* __restrict__ base, unsigned* __restrict__ curn) {
    int i4 = blockIdx.x * 256 + threadIdx.x;
    int node = i4 >> 4;
    int isbf = flags[0];
    float m = mask01[node];
    int lab = label[node];
    float nrm = norm[node], sc = scale[node];
    int c0 = (i4 & 15) * 4;
    float4 ys;
    if (isbf) {
        ushort4 u = ((const ushort4*)ysoft)[i4];
        ys.x = __uint_as_float((unsigned)u.x << 16);
        ys.y = __uint_as_float((unsigned)u.y << 16);
        ys.z = __uint_as_float((unsigned)u.z << 16);
        ys.w = __uint_as_float((unsigned)u.w << 16);
    } else {
        ys = ((const float4*)ysoft)[i4];
    }
    float4 sm = ((const float4*)smoothed)[i4];
    float rx = ys.x + sc * sm.x; if (isnan(rx)) rx = ys.x;
    float ry = ys.y + sc * sm.y; if (isnan(ry)) ry = ys.y;
    float rz = ys.z + sc * sm.z; if (isnan(rz)) rz = ys.z;
    float rw = ys.w + sc * sm.w; if (isnan(rw)) rw = ys.w;
    float4 y;
    y.x = (m != 0.f) ? ((c0 + 0 == lab) ? 1.f : 0.f) : rx;
    y.y = (m != 0.f) ? ((c0 + 1 == lab) ? 1.f : 0.f) : ry;
    y.z = (m != 0.f) ? ((c0 + 2 == lab) ? 1.f : 0.f) : rz;
    y.w = (m != 0.f) ? ((c0 + 3 == lab) ? 1.f : 0.f) : rw;
    ((float4*)base)[i4] = y;
    ((uint2*)curn)[i4] = make_uint2(pack_bf16(y.x * nrm, y.y * nrm),
                                    pack_bf16(y.z * nrm, y.w * nrm));
}

extern "C" void kernel_launch(void* const* d_in, const int* in_sizes, int n_in,
                              void* d_out, int out_size, void* d_ws, size_t ws_size,
                              hipStream_t stream) {
    const void* ysoft = d_in[0];
    const void* ytrue = d_in[1];
    const int* src = (const int*)d_in[2];
    const int* dst = (const int*)d_in[3];
    const void* mask = d_in[4];

    char* ws = (char*)d_ws;
    int*   flags     = (int*)ws;                   // zeroed
    float* scal      = (float*)(ws + 64);
    int*   partials  = (int*)(ws + 4096);
    int*   chunk_off = (int*)(ws + 8192);
    float* err_part  = (float*)(ws + 12288);       // ERR_BLOCKS floats
    int*   degi      = (int*)(ws + 40960);         // NN ints, zeroed
    size_t ZERO_BYTES = 40960 + (size_t)NN * 4;

    size_t off = (ZERO_BYTES + 255) & ~(size_t)255;
    int*   label   = (int*)(ws + off);   off += (size_t)NN * 4;
    float* mask01  = (float*)(ws + off); off += (size_t)NN * 4;
    float* norm    = (float*)(ws + off); off += (size_t)NN * 4;
    float* scale   = (float*)(ws + off); off += (size_t)NN * 4;
    float* rowsum  = (float*)(ws + off); off += (size_t)NN * 4;
    int*   row_ptr = (int*)(ws + off);   off += (size_t)(NN + 1) * 4;
    int*   cursor  = (int*)(ws + off);   off += (size_t)NN * 4;
    off = (off + 255) & ~(size_t)255;
    int*   csr_src  = (int*)(ws + off);      off += (size_t)EE * 4;
    off = (off + 255) & ~(size_t)255;
    float*    base     = (float*)(ws + off);    off += (size_t)NC * 4;
    float*    smoothed = (float*)(ws + off);    off += (size_t)NC * 4;
    unsigned* bufA     = (unsigned*)(ws + off); off += (size_t)NC * 2;
    unsigned* bufB     = (unsigned*)(ws + off); off += (size_t)NC * 2;

    hipMemsetAsync(ws, 0, ZERO_BYTES, stream);

    detect_kernel<<<1, 256, 0, stream>>>(ytrue, mask, flags);
    prep_kernel<<<(NN * 64 + 255) / 256, 256, 0, stream>>>(ytrue, mask, flags, label, mask01);
    deg_kernel<<<(EE + 255) / 256, 256, 0, stream>>>(dst, degi);
    norm_kernel<<<(NN + 255) / 256, 256, 0, stream>>>(degi, norm);
    scan1_kernel<<<SCAN_BLOCKS, 256, 0, stream>>>(degi, partials);
    scan2_kernel<<<1, 512, 0, stream>>>(partials, chunk_off);
    scan3_kernel<<<SCAN_BLOCKS, 256, 0, stream>>>(degi, chunk_off, row_ptr, cursor);
    fill_kernel<<<(EE + 255) / 256, 256, 0, stream>>>(src, dst, cursor, csr_src);
    err_kernel<<<ERR_BLOCKS, 256, 0, stream>>>(ysoft, flags, label, mask01, norm, base, bufA, err_part);
    reduce_kernel<<<1, 1024, 0, stream>>>(mask01, err_part, scal);

    const int gather_blocks = (NN * 64 + 255) / 256;

    // ---- correct phase: 10 layers, alpha=0.979, clip [-1,1]
    unsigned* cur = bufA; unsigned* nxt = bufB;
    for (int l = 0; l < 10; l++) {
        int mode = (l < 9) ? 0 : 1;
        void* o = (l < 9) ? (void*)nxt : (void*)smoothed;
        gather_kernel<<<gather_blocks, 256, 0, stream>>>(row_ptr, csr_src, cur, base, norm, o,
                                                         rowsum, flags, 0.979f, -1.f, 1.f, mode);
        unsigned* t = cur; cur = nxt; nxt = t;
    }
    // NOTE: after mode-1 layer the swap is harmless; smoothed holds fp32 result

    scale_kernel<<<(NN + 255) / 256, 256, 0, stream>>>(rowsum, scal, scale);
    y0_kernel<<<ERR_BLOCKS, 256, 0, stream>>>(ysoft, flags, label, mask01, scale, norm,
                                              smoothed, base, bufA);

    // ---- smooth phase: 10 layers, alpha=0.756, clip [0,1]; last writes d_out
    cur = bufA; nxt = bufB;
    for (int l = 0; l < 10; l++) {
        int mode = (l < 9) ? 0 : 3;
        void* o = (l < 9) ? (void*)nxt : (void*)d_out;
        gather_kernel<<<gather_blocks, 256, 0, stream>>>(row_ptr, csr_src, cur, base, norm, o,
                                                         rowsum, flags, 0.756f, 0.f, 1.f, mode);
        unsigned* t = cur; cur = nxt; nxt = t;
    }
}